// Round 2
// baseline (4330.651 us; speedup 1.0000x reference)
//
#include <hip/hip_runtime.h>

// LocalAttention (Swin-style, scrambled-window variant), fp32, fully fused per pass.
//
// Window mapping (derived from reference reshape/transpose, C=64, H=W=256, ws=8):
//   flat = ((((b*64+c)*32+hn)*32+wn)*8+r)*8+s  reinterpreted as (n, c2, p):
//   n = b*1024 + c*16 + t   (t = hn>>1)
//   c2 = (hn&1)*32 + wn = hi*32+lo ;  p = r*8+s ;  h = 16t+8hi+r ; w = 8lo+s
// Mask applied by raw index n%1023+1... i.e. mask[n & 1023] with mask built for
// "true" window (m>>5, m&31) — the reference applies it by raw index; we replicate.
//
// One block = one window (8192 blocks x 256 threads). Phases:
//   1 load(+shift roll)  2 1x1 conv  3 dw3x3  4 l2norm(q,k)  5 QK^T+mask+softmax
//   6 A*V  7 3x3 proj conv  8 window-reverse(+roll) store
// All LDS layouts chosen conflict-free (<=2-way) per the 32-bank model.

#define TPB 256
#define SIN_STRIDE 72   // 64-pixel rows padded to 72: staging ds_write 2-way (free)
#define SOUT_OFF   4096 // s_out lives in dead k/v-plane region of s_qkv
#define SOUT_STRIDE 72

// ---------------- weight transpose for proj: wpT[(ic*9+tap)*64+oc] ----------------
__global__ void k_wt(const float* __restrict__ wp, float* __restrict__ wpT) {
    int idx = blockIdx.x * 256 + threadIdx.x;
    if (idx >= 64 * 64 * 9) return;
    int oc = idx & 63;
    int tmp = idx >> 6;
    int tp = tmp % 9, ic = tmp / 9;
    wpT[idx] = wp[(oc * 64 + ic) * 9 + tp];
}

__global__ __launch_bounds__(TPB, 2)
void k_fused(const float* __restrict__ in, const float* __restrict__ wqkv,
             const float* __restrict__ wdw, const float* __restrict__ wpT,
             float* __restrict__ out, int shift, int use_mask, int roll)
{
    __shared__ float s_in[64 * SIN_STRIDE]; // input window [c2][p]; later attn[i][j]
    __shared__ float s_qkv[192 * 64];       // q(0..63) k(64..127) v(128..191) [ch][p]

    const int tid = threadIdx.x;
    const int lane = tid & 63;
    const int wv = tid >> 6;
    const int n = blockIdx.x;
    const int b = n >> 10, c = (n >> 4) & 63, t = n & 15;
    const size_t base = ((size_t)(b * 64 + c)) << 16;

    // ---- phase 1: load window (coalesced rows; shift roll folded in) ----
    #pragma unroll
    for (int k = 0; k < 16; ++k) {
        int o = tid + k * 256;
        int hi = o >> 11, r = (o >> 8) & 7, lo = (o >> 3) & 31, s = o & 7;
        int h = t * 16 + hi * 8 + r, w2 = lo * 8 + s;
        float v = in[base + (size_t)((h + shift) & 255) * 256 + ((w2 + shift) & 255)];
        s_in[(hi * 32 + lo) * SIN_STRIDE + r * 8 + s] = v;
    }
    __syncthreads();

    // ---- phase 2: 1x1 conv. wave wv owns oc [wv*48, wv*48+48); lane = pixel ----
    const int oc0 = wv * 48;
    {
        float acc[48];
        #pragma unroll
        for (int q = 0; q < 48; ++q) acc[q] = 0.f;
        for (int ic = 0; ic < 64; ic += 4) {
            float x0 = s_in[(ic + 0) * SIN_STRIDE + lane];
            float x1 = s_in[(ic + 1) * SIN_STRIDE + lane];
            float x2 = s_in[(ic + 2) * SIN_STRIDE + lane];
            float x3 = s_in[(ic + 3) * SIN_STRIDE + lane];
            #pragma unroll
            for (int q = 0; q < 48; ++q) {
                const float4 wr = *(const float4*)&wqkv[(oc0 + q) * 64 + ic];
                acc[q] += wr.x * x0 + wr.y * x1 + wr.z * x2 + wr.w * x3;
            }
        }
        #pragma unroll
        for (int q = 0; q < 48; ++q) s_qkv[(oc0 + q) * 64 + lane] = acc[q];
    }
    __syncthreads();

    // ---- phase 3: depthwise 3x3, window-local zero pad; wave owns its planes ----
    {
        const int r = lane >> 3, s = lane & 7;
        float dwv[48];
        #pragma unroll
        for (int q = 0; q < 48; ++q) {
            const int oc = oc0 + q;
            const float* wd = &wdw[oc * 9];
            const float* pl = &s_qkv[oc * 64];
            float a = 0.f;
            #pragma unroll
            for (int dy = -1; dy <= 1; ++dy) {
                int rr = r + dy;
                if ((unsigned)rr < 8u) {
                    #pragma unroll
                    for (int dx = -1; dx <= 1; ++dx) {
                        int cc = s + dx;
                        if ((unsigned)cc < 8u)
                            a += wd[(dy + 1) * 3 + (dx + 1)] * pl[rr * 8 + cc];
                    }
                }
            }
            dwv[q] = a;
        }
        // same-wave LDS ordering: all reads above precede these writes
        #pragma unroll
        for (int q = 0; q < 48; ++q) s_qkv[(oc0 + q) * 64 + lane] = dwv[q];
    }
    __syncthreads();

    // ---- phase 4: l2norm over hw for q,k (ch 0..127); rotated -> conflict-free ----
    if (tid < 128) {
        float ssq = 0.f;
        #pragma unroll 8
        for (int i = 0; i < 64; ++i) {
            float v = s_qkv[tid * 64 + ((tid + i) & 63)];
            ssq += v * v;
        }
        float sc = 1.f / fmaxf(sqrtf(ssq), 1e-12f);
        #pragma unroll 8
        for (int i = 0; i < 64; ++i) s_qkv[tid * 64 + ((tid + i) & 63)] *= sc;
    }
    __syncthreads();

    // ---- phase 5: attn[i][j] = sum_c q[c][i] k[c][j] /8 (+mask); softmax over j ----
    const int i0 = wv * 16;
    {
        float at[16];
        #pragma unroll
        for (int ii = 0; ii < 16; ++ii) at[ii] = 0.f;
        for (int c2 = 0; c2 < 64; ++c2) {
            float kv = s_qkv[(64 + c2) * 64 + lane];          // lane = j
            const float4* qp = (const float4*)&s_qkv[c2 * 64 + i0]; // broadcast
            float4 q0 = qp[0], q1 = qp[1], q2 = qp[2], q3 = qp[3];
            at[0] += q0.x * kv;  at[1] += q0.y * kv;  at[2] += q0.z * kv;  at[3] += q0.w * kv;
            at[4] += q1.x * kv;  at[5] += q1.y * kv;  at[6] += q1.z * kv;  at[7] += q1.w * kv;
            at[8] += q2.x * kv;  at[9] += q2.y * kv;  at[10] += q2.z * kv; at[11] += q2.w * kv;
            at[12] += q3.x * kv; at[13] += q3.y * kv; at[14] += q3.z * kv; at[15] += q3.w * kv;
        }
        if (use_mask) {
            const int widx = n & 1023;
            const int hn_m = widx >> 5, wn_m = widx & 31;
            const int rj = ((hn_m == 31) ? (((lane >> 3) < 4) ? 1 : 2) : 0) * 3
                         + ((wn_m == 31) ? (((lane & 7) < 4) ? 1 : 2) : 0);
            #pragma unroll
            for (int ii = 0; ii < 16; ++ii) {
                int i = i0 + ii;
                int ri = ((hn_m == 31) ? (((i >> 3) < 4) ? 1 : 2) : 0) * 3
                       + ((wn_m == 31) ? (((i & 7) < 4) ? 1 : 2) : 0);
                at[ii] = at[ii] * 0.125f + ((ri != rj) ? -100.f : 0.f);
            }
        } else {
            #pragma unroll
            for (int ii = 0; ii < 16; ++ii) at[ii] *= 0.125f;
        }
        #pragma unroll
        for (int ii = 0; ii < 16; ++ii) {
            float v = at[ii];
            float mx = v;
            #pragma unroll
            for (int off = 32; off > 0; off >>= 1) mx = fmaxf(mx, __shfl_xor(mx, off, 64));
            float e = __expf(v - mx);
            float sm = e;
            #pragma unroll
            for (int off = 32; off > 0; off >>= 1) sm += __shfl_xor(sm, off, 64);
            s_in[(i0 + ii) * SIN_STRIDE + lane] = e / sm;  // attn row (input dead)
        }
    }
    __syncthreads();

    // ---- phase 6: out[c][j] = sum_i v[c][i] attn[i][j] -> dead q-planes of s_qkv ----
    {
        float ov[16];
        #pragma unroll
        for (int cc = 0; cc < 16; ++cc) ov[cc] = 0.f;
        const int cb = 128 + wv * 16;  // my v channels
        for (int iq = 0; iq < 64; iq += 4) {
            float a0 = s_in[(iq + 0) * SIN_STRIDE + lane];
            float a1 = s_in[(iq + 1) * SIN_STRIDE + lane];
            float a2 = s_in[(iq + 2) * SIN_STRIDE + lane];
            float a3 = s_in[(iq + 3) * SIN_STRIDE + lane];
            #pragma unroll
            for (int cc = 0; cc < 16; ++cc) {
                const float4 vv = *(const float4*)&s_qkv[(cb + cc) * 64 + iq]; // broadcast
                ov[cc] += vv.x * a0 + vv.y * a1 + vv.z * a2 + vv.w * a3;
            }
        }
        #pragma unroll
        for (int cc = 0; cc < 16; ++cc)
            s_qkv[(wv * 16 + cc) * 64 + lane] = ov[cc];   // planes 0..63 = attn out
    }
    __syncthreads();

    // ---- phase 7: 3x3 proj conv. lane = oc; wave wv owns rows r0, r0+1 ----
    {
        const int r0 = wv * 2;
        float accp[16];
        #pragma unroll
        for (int j = 0; j < 16; ++j) accp[j] = 0.f;

        for (int ic = 0; ic < 64; ++ic) {
            float xv[4][10];  // rows r0-1..r0+2, cols -1..8, window-local zero pad
            #pragma unroll
            for (int k = 0; k < 4; ++k) {
                int rr = r0 - 1 + k;
                xv[k][0] = 0.f; xv[k][9] = 0.f;
                if ((unsigned)rr < 8u) {
                    const float4* rp = (const float4*)&s_qkv[ic * 64 + rr * 8]; // broadcast
                    float4 aa = rp[0], bb = rp[1];
                    xv[k][1] = aa.x; xv[k][2] = aa.y; xv[k][3] = aa.z; xv[k][4] = aa.w;
                    xv[k][5] = bb.x; xv[k][6] = bb.y; xv[k][7] = bb.z; xv[k][8] = bb.w;
                } else {
                    #pragma unroll
                    for (int q = 1; q < 9; ++q) xv[k][q] = 0.f;
                }
            }
            float wt[9];
            #pragma unroll
            for (int tp = 0; tp < 9; ++tp) wt[tp] = wpT[(ic * 9 + tp) * 64 + lane];
            #pragma unroll
            for (int rl = 0; rl < 2; ++rl)
                #pragma unroll
                for (int s = 0; s < 8; ++s) {
                    float a = 0.f;
                    #pragma unroll
                    for (int dy = 0; dy < 3; ++dy)
                        #pragma unroll
                        for (int dx = 0; dx < 3; ++dx)
                            a += wt[dy * 3 + dx] * xv[rl + dy][s + dx];
                    accp[rl * 8 + s] += a;
                }
        }
        float* so = &s_qkv[SOUT_OFF];   // k/v planes dead; [oc][p] stride 72
        #pragma unroll
        for (int j = 0; j < 16; ++j) so[lane * SOUT_STRIDE + r0 * 8 + j] = accp[j];
    }
    __syncthreads();

    // ---- phase 8: window reverse + roll, coalesced image-order writes ----
    {
        const float* so = &s_qkv[SOUT_OFF];
        #pragma unroll
        for (int k = 0; k < 16; ++k) {
            int o = tid + k * 256;
            int hi = o >> 11, r = (o >> 8) & 7, lo = (o >> 3) & 31, s = o & 7;
            int c2 = hi * 32 + lo;
            float v = so[c2 * SOUT_STRIDE + r * 8 + s];
            int h = t * 16 + hi * 8 + r, w2 = lo * 8 + s;
            out[base + (size_t)((h + roll) & 255) * 256 + ((w2 + roll) & 255)] = v;
        }
    }
}

extern "C" void kernel_launch(void* const* d_in, const int* in_sizes, int n_in,
                              void* d_out, int out_size, void* d_ws, size_t ws_size,
                              hipStream_t stream)
{
    const float* x      = (const float*)d_in[0];
    const float* wqkv0  = (const float*)d_in[1];
    const float* wdw0   = (const float*)d_in[2];
    const float* wproj0 = (const float*)d_in[3];
    const float* wqkv1  = (const float*)d_in[4];
    const float* wdw1   = (const float*)d_in[5];
    const float* wproj1 = (const float*)d_in[6];
    float* out = (float*)d_out;

    float* tmp  = (float*)d_ws;                  // 33,554,432 floats (134 MB)
    float* wpT0 = tmp + 33554432;                // 36,864 floats
    float* wpT1 = wpT0 + 36864;

    hipLaunchKernelGGL(k_wt, dim3(144), dim3(256), 0, stream, wproj0, wpT0);
    hipLaunchKernelGGL(k_wt, dim3(144), dim3(256), 0, stream, wproj1, wpT1);

    // pass 1: x -> tmp (no shift, no mask, no roll)
    hipLaunchKernelGGL(k_fused, dim3(8192), dim3(TPB), 0, stream,
                       x, wqkv0, wdw0, wpT0, tmp, 0, 0, 0);
    // pass 2: tmp -> out (shift +4 on read, Swin mask, final roll +4 on write)
    hipLaunchKernelGGL(k_fused, dim3(8192), dim3(TPB), 0, stream,
                       tmp, wqkv1, wdw1, wpT1, out, 4, 1, 4);
}

// Round 3
// 1170.784 us; speedup vs baseline: 3.6989x; 3.6989x over previous
//
#include <hip/hip_runtime.h>

// LocalAttention (Swin-style, scrambled-window variant) — MFMA split-bf16 version.
// Window map (verified in R2, passed): n=b*1024+c*16+t ; c2=hi*32+lo ; p=r*8+s ;
// h=16t+8hi+r ; w=8lo+s ; mask index = n&1023.
//
// Per block (= one 64ch x 8x8 window), phases:
//  P1 load+split -> XTin bf16 [p][c2]           P5 QK^T fp32 (readlane bcast) + softmax -> attnT bf16
//  P2 MFMA 1x1 qkv (bf16x3) -> q,k fp32 planes + v fp32   P6 MFMA A*V -> XT(attn-out) bf16 [p][c]
//  P3 dw3x3 row-tasks -> q,k planes ; v -> vbf bf16       P7 MFMA proj conv (9 shifted GEMMs)
//  P4 l2norm(q,k) fp32                                    P8 window-reverse + roll store
// Split-bf16: x = hi + lo, D += Ah*Bh + Ah*Bl + Al*Bh  (error ~2^-18 rel).

typedef __attribute__((ext_vector_type(8))) short bf8;
typedef __attribute__((ext_vector_type(4))) float f32x4;
#define MFMA(a, b, c) __builtin_amdgcn_mfma_f32_16x16x32_bf16(a, b, c, 0, 0, 0)

__device__ __forceinline__ void bsplit(float f, short& h, short& l) {
    unsigned u = __float_as_uint(f);
    unsigned hb = (u + 0x7FFFu + ((u >> 16) & 1u)) >> 16;
    float hf = __uint_as_float(hb << 16);
    float r = f - hf;
    unsigned u2 = __float_as_uint(r);
    unsigned lb = (u2 + 0x7FFFu + ((u2 >> 16) & 1u)) >> 16;
    h = (short)hb; l = (short)lb;
}

// ---- qkv 1x1 weight fragments: [kk(2)][tt(12)][lane(64)][j(8)]  B[k=ic][n=oc] ----
__global__ void k_fq(const float* __restrict__ wq, short* __restrict__ oh, short* __restrict__ ol) {
    int bx = blockIdx.x;                 // kk*12 + tt
    int kk = bx / 12, tt = bx % 12;
    int tid = threadIdx.x;               // 512
    int lane = tid >> 3, j = tid & 7;
    int oc = tt * 16 + (lane & 15);
    int ic = kk * 32 + ((lane >> 4) << 3) + j;
    short h, l; bsplit(wq[oc * 64 + ic], h, l);
    oh[bx * 512 + tid] = h; ol[bx * 512 + tid] = l;
}

// ---- proj 3x3 weight fragments: [tap(9)][kk(2)][tt(4)][lane(64)][j(8)] ----
__global__ void k_fp(const float* __restrict__ wp, short* __restrict__ oh, short* __restrict__ ol) {
    int bx = blockIdx.x;                 // tap*8 + kk*4 + tt
    int tap = bx >> 3, kk = (bx >> 2) & 1, tt = bx & 3;
    int tid = threadIdx.x;
    int lane = tid >> 3, j = tid & 7;
    int oc = tt * 16 + (lane & 15);
    int ic = kk * 32 + ((lane >> 4) << 3) + j;
    short h, l; bsplit(wp[(oc * 64 + ic) * 9 + tap], h, l);
    oh[bx * 512 + tid] = h; ol[bx * 512 + tid] = l;
}

__global__ __launch_bounds__(256, 2)
void k_fused(const float* __restrict__ in,
             const short* __restrict__ bqh, const short* __restrict__ bql,
             const float* __restrict__ wdw,
             const short* __restrict__ bph, const short* __restrict__ bpl,
             float* __restrict__ out, int shift, int use_mask, int roll)
{
    __shared__ float s_qk[128 * 68];                    // q,k fp32 planes; later proj-out
    __shared__ __align__(16) short s_ov[2][65 * 72];    // XTin -> attnT -> XT(attn-out)+zero row
    __shared__ __align__(16) short s_vb[2][64 * 72];    // v fp32 overlay -> vbf bf16

    float* vtmpf = (float*)&s_vb[0][0];                 // 64 x 68 fp32 (pre-dw v)
    short* XTh = &s_ov[0][0];
    short* XTl = &s_ov[1][0];

    const int tid = threadIdx.x, lane = tid & 63, wv = tid >> 6;
    const int col = lane & 15, quad = lane >> 4, qo8 = quad * 8;
    const int mh = wv & 1, nh = wv >> 1;
    const int n = blockIdx.x;
    const int b = n >> 10, c = (n >> 4) & 63, t = n & 15;
    const size_t base = ((size_t)(b * 64 + c)) << 16;

    // ---- P1: load window (shift folded), split to bf16, XTin[p][c2] ----
    #pragma unroll
    for (int k = 0; k < 16; ++k) {
        int o = tid + k * 256;
        int hi = o >> 11, r = (o >> 8) & 7, lo = (o >> 3) & 31, s = o & 7;
        int h2 = t * 16 + hi * 8 + r, w2 = lo * 8 + s;
        float v = in[base + (size_t)((h2 + shift) & 255) * 256 + ((w2 + shift) & 255)];
        short hh, ll; bsplit(v, hh, ll);
        int p = r * 8 + s, c2 = hi * 32 + lo;
        XTh[p * 72 + c2] = hh; XTl[p * 72 + c2] = ll;
    }
    __syncthreads();

    // ---- P2: MFMA 1x1 conv. M=p(64), N=oc(192), K=ic(64). wave: 2 m-tiles x 6 n-tiles ----
    {
        f32x4 acc[2][6];
        #pragma unroll
        for (int mt = 0; mt < 2; ++mt)
            #pragma unroll
            for (int nt = 0; nt < 6; ++nt) acc[mt][nt] = (f32x4){0.f, 0.f, 0.f, 0.f};
        #pragma unroll
        for (int kk = 0; kk < 2; ++kk) {
            bf8 Ah[2], Al[2];
            #pragma unroll
            for (int mt = 0; mt < 2; ++mt) {
                int ad = ((mh * 2 + mt) * 16 + col) * 72 + kk * 32 + qo8;
                Ah[mt] = *(const bf8*)&XTh[ad];
                Al[mt] = *(const bf8*)&XTl[ad];
            }
            #pragma unroll
            for (int nt = 0; nt < 6; ++nt) {
                int tt = nh * 6 + nt;
                bf8 Bh = *(const bf8*)&bqh[((kk * 12 + tt) * 64 + lane) * 8];
                bf8 Bl = *(const bf8*)&bql[((kk * 12 + tt) * 64 + lane) * 8];
                #pragma unroll
                for (int mt = 0; mt < 2; ++mt) {
                    acc[mt][nt] = MFMA(Ah[mt], Bh, acc[mt][nt]);
                    acc[mt][nt] = MFMA(Ah[mt], Bl, acc[mt][nt]);
                    acc[mt][nt] = MFMA(Al[mt], Bh, acc[mt][nt]);
                }
            }
        }
        #pragma unroll
        for (int nt = 0; nt < 6; ++nt) {
            int oc = (nh * 6 + nt) * 16 + col;
            float* dst = (oc < 128) ? (s_qk + oc * 68) : (vtmpf + (oc - 128) * 68);
            #pragma unroll
            for (int mt = 0; mt < 2; ++mt) {
                int p0 = (mh * 2 + mt) * 16 + quad * 4;
                #pragma unroll
                for (int r = 0; r < 4; ++r) dst[p0 + r] = acc[mt][nt][r];
            }
        }
    }
    __syncthreads();

    // ---- P3a: dw3x3 row-tasks (task = it*256+tid -> ch=t>>3, row=t&7), into regs ----
    float dwo[6][8];
    {
        #pragma unroll
        for (int it = 0; it < 6; ++it) {
            int tk = it * 256 + tid;
            int ch = tk >> 3, row = tk & 7;
            const float* pl = (ch < 128) ? (s_qk + ch * 68) : (vtmpf + (ch - 128) * 68);
            const float* wd = wdw + ch * 9;
            float e[3][10];
            #pragma unroll
            for (int k3 = 0; k3 < 3; ++k3) {
                int rr = row - 1 + k3;
                e[k3][0] = 0.f; e[k3][9] = 0.f;
                if ((unsigned)rr < 8u) {
                    float4 a = *(const float4*)&pl[rr * 8];
                    float4 bq = *(const float4*)&pl[rr * 8 + 4];
                    e[k3][1] = a.x;  e[k3][2] = a.y;  e[k3][3] = a.z;  e[k3][4] = a.w;
                    e[k3][5] = bq.x; e[k3][6] = bq.y; e[k3][7] = bq.z; e[k3][8] = bq.w;
                } else {
                    #pragma unroll
                    for (int q2 = 1; q2 < 9; ++q2) e[k3][q2] = 0.f;
                }
            }
            float w9[9];
            #pragma unroll
            for (int tp = 0; tp < 9; ++tp) w9[tp] = wd[tp];
            #pragma unroll
            for (int s = 0; s < 8; ++s) {
                float a = 0.f;
                #pragma unroll
                for (int k3 = 0; k3 < 3; ++k3)
                    #pragma unroll
                    for (int dx = 0; dx < 3; ++dx)
                        a = fmaf(w9[k3 * 3 + dx], e[k3][s + dx], a);
                dwo[it][s] = a;
            }
        }
    }
    __syncthreads();   // all plane reads done before in-place writes

    // ---- P3b: write back. q,k -> fp32 planes; v -> vbf bf16 [c][i] (overlays vtmp) ----
    {
        #pragma unroll
        for (int it = 0; it < 6; ++it) {
            int tk = it * 256 + tid;
            int ch = tk >> 3, row = tk & 7;
            if (ch < 128) {
                float* dst = s_qk + ch * 68 + row * 8;
                *(float4*)dst       = (float4){dwo[it][0], dwo[it][1], dwo[it][2], dwo[it][3]};
                *(float4*)(dst + 4) = (float4){dwo[it][4], dwo[it][5], dwo[it][6], dwo[it][7]};
            } else {
                uint hw[4], lw[4];
                #pragma unroll
                for (int q2 = 0; q2 < 4; ++q2) {
                    short h0, l0, h1, l1;
                    bsplit(dwo[it][2 * q2], h0, l0);
                    bsplit(dwo[it][2 * q2 + 1], h1, l1);
                    hw[q2] = (uint)(ushort)h0 | ((uint)(ushort)h1 << 16);
                    lw[q2] = (uint)(ushort)l0 | ((uint)(ushort)l1 << 16);
                }
                int ad = (ch - 128) * 72 + row * 8;
                *(uint4*)&s_vb[0][ad] = (uint4){hw[0], hw[1], hw[2], hw[3]};
                *(uint4*)&s_vb[1][ad] = (uint4){lw[0], lw[1], lw[2], lw[3]};
            }
        }
    }
    __syncthreads();

    // ---- P4: l2norm q,k (channel = tid<128), rotated conflict-free ----
    if (tid < 128) {
        float* plq = s_qk + tid * 68;
        float ssq = 0.f;
        #pragma unroll 8
        for (int i = 0; i < 64; ++i) {
            float v = plq[(tid + i) & 63];
            ssq = fmaf(v, v, ssq);
        }
        float sc = 1.f / fmaxf(sqrtf(ssq), 1e-12f);
        #pragma unroll 8
        for (int i = 0; i < 64; ++i) plq[(tid + i) & 63] *= sc;
    }
    __syncthreads();

    // ---- P5: QK^T fp32 (q via readlane broadcast) + mask + softmax -> attnT bf16 ----
    {
        const int i0 = wv * 16;
        float qr[16];
        #pragma unroll
        for (int ii = 0; ii < 4; ++ii) {
            float4 qv = *(const float4*)&s_qk[lane * 68 + i0 + ii * 4];
            qr[4 * ii + 0] = qv.x; qr[4 * ii + 1] = qv.y;
            qr[4 * ii + 2] = qv.z; qr[4 * ii + 3] = qv.w;
        }
        float at[16];
        #pragma unroll
        for (int ii = 0; ii < 16; ++ii) at[ii] = 0.f;
        for (int c2 = 0; c2 < 64; ++c2) {
            float kv = s_qk[(64 + c2) * 68 + lane];
            #pragma unroll
            for (int ii = 0; ii < 16; ++ii) {
                float qs = __uint_as_float(
                    __builtin_amdgcn_readlane(__float_as_uint(qr[ii]), c2));
                at[ii] = fmaf(qs, kv, at[ii]);
            }
        }
        if (use_mask) {
            const int widx = n & 1023;
            const int hn_m = widx >> 5, wn_m = widx & 31;
            const int rj = ((hn_m == 31) ? (((lane >> 3) < 4) ? 1 : 2) : 0) * 3
                         + ((wn_m == 31) ? (((lane & 7) < 4) ? 1 : 2) : 0);
            #pragma unroll
            for (int ii = 0; ii < 16; ++ii) {
                int i = i0 + ii;
                int ri = ((hn_m == 31) ? (((i >> 3) < 4) ? 1 : 2) : 0) * 3
                       + ((wn_m == 31) ? (((i & 7) < 4) ? 1 : 2) : 0);
                at[ii] = at[ii] * 0.125f + ((ri != rj) ? -100.f : 0.f);
            }
        } else {
            #pragma unroll
            for (int ii = 0; ii < 16; ++ii) at[ii] *= 0.125f;
        }
        float sv[16];
        #pragma unroll
        for (int ii = 0; ii < 16; ++ii) {
            float v = at[ii];
            float mx = v;
            #pragma unroll
            for (int off = 32; off > 0; off >>= 1) mx = fmaxf(mx, __shfl_xor(mx, off, 64));
            float e2 = __expf(v - mx);
            float sm = e2;
            #pragma unroll
            for (int off = 32; off > 0; off >>= 1) sm += __shfl_xor(sm, off, 64);
            sv[ii] = e2 / sm;
        }
        // attnT[j=lane][i] bf16 hi/lo, packed pair writes
        #pragma unroll
        for (int ii = 0; ii < 16; ii += 2) {
            short h0, l0, h1, l1;
            bsplit(sv[ii], h0, l0); bsplit(sv[ii + 1], h1, l1);
            int ad = lane * 72 + i0 + ii;
            *(uint*)&XTh[ad] = (uint)(ushort)h0 | ((uint)(ushort)h1 << 16);
            *(uint*)&XTl[ad] = (uint)(ushort)l0 | ((uint)(ushort)l1 << 16);
        }
    }
    __syncthreads();

    // ---- P6: MFMA A*V. M=c(64), N=j(64), K=i(64). A=vbf[c][i], B=attnT[j][i] ----
    {
        f32x4 accv[2][2];
        #pragma unroll
        for (int mt = 0; mt < 2; ++mt)
            #pragma unroll
            for (int nt = 0; nt < 2; ++nt) accv[mt][nt] = (f32x4){0.f, 0.f, 0.f, 0.f};
        #pragma unroll
        for (int kk = 0; kk < 2; ++kk) {
            bf8 Ah[2], Al[2], Bh[2], Bl[2];
            #pragma unroll
            for (int mt = 0; mt < 2; ++mt) {
                int ad = ((mh * 2 + mt) * 16 + col) * 72 + kk * 32 + qo8;
                Ah[mt] = *(const bf8*)&s_vb[0][ad];
                Al[mt] = *(const bf8*)&s_vb[1][ad];
            }
            #pragma unroll
            for (int nt = 0; nt < 2; ++nt) {
                int ad = ((nh * 2 + nt) * 16 + col) * 72 + kk * 32 + qo8;
                Bh[nt] = *(const bf8*)&XTh[ad];
                Bl[nt] = *(const bf8*)&XTl[ad];
            }
            #pragma unroll
            for (int mt = 0; mt < 2; ++mt)
                #pragma unroll
                for (int nt = 0; nt < 2; ++nt) {
                    accv[mt][nt] = MFMA(Ah[mt], Bh[nt], accv[mt][nt]);
                    accv[mt][nt] = MFMA(Ah[mt], Bl[nt], accv[mt][nt]);
                    accv[mt][nt] = MFMA(Al[mt], Bh[nt], accv[mt][nt]);
                }
        }
        __syncthreads();   // attnT reads done; region becomes XT(attn-out)
        // D[c][j] -> XT[p=j][ic=c] bf16, packed over r-pairs; + zero row 64
        #pragma unroll
        for (int nt = 0; nt < 2; ++nt) {
            int j = (nh * 2 + nt) * 16 + col;
            #pragma unroll
            for (int mt = 0; mt < 2; ++mt) {
                int c0 = (mh * 2 + mt) * 16 + quad * 4;
                #pragma unroll
                for (int rp = 0; rp < 2; ++rp) {
                    short h0, l0, h1, l1;
                    bsplit(accv[mt][nt][2 * rp], h0, l0);
                    bsplit(accv[mt][nt][2 * rp + 1], h1, l1);
                    int ad = j * 72 + c0 + 2 * rp;
                    *(uint*)&XTh[ad] = (uint)(ushort)h0 | ((uint)(ushort)h1 << 16);
                    *(uint*)&XTl[ad] = (uint)(ushort)l0 | ((uint)(ushort)l1 << 16);
                }
            }
        }
        if (tid < 32) {
            ((uint*)XTh)[(64 * 72) / 2 + tid] = 0u;
            ((uint*)XTl)[(64 * 72) / 2 + tid] = 0u;
        }
    }
    __syncthreads();

    // ---- P7: MFMA proj conv = 9 shifted GEMMs. M=p, N=oc, K=ic ----
    {
        f32x4 accp[2][2];
        #pragma unroll
        for (int mt = 0; mt < 2; ++mt)
            #pragma unroll
            for (int nt = 0; nt < 2; ++nt) accp[mt][nt] = (f32x4){0.f, 0.f, 0.f, 0.f};
        const int smc = col & 7;
        #pragma unroll 1
        for (int tap = 0; tap < 9; ++tap) {
            int dy = (tap >= 6) ? 1 : ((tap >= 3) ? 0 : -1);
            int dx = tap - (dy + 1) * 3 - 1;
            int ra[2];
            #pragma unroll
            for (int mt = 0; mt < 2; ++mt) {
                int rr = (mh * 2 + mt) * 2 + (col >> 3) + dy;
                int ss = smc + dx;
                bool ok = ((unsigned)rr < 8u) && ((unsigned)ss < 8u);
                ra[mt] = (ok ? (rr * 8 + ss) : 64) * 72;   // row 64 = zeros
            }
            #pragma unroll
            for (int kk = 0; kk < 2; ++kk) {
                bf8 Bh[2], Bl[2], Ah[2], Al[2];
                #pragma unroll
                for (int nt = 0; nt < 2; ++nt) {
                    int bi = (((tap * 2 + kk) * 4 + (nh * 2 + nt)) * 64 + lane) * 8;
                    Bh[nt] = *(const bf8*)&bph[bi];
                    Bl[nt] = *(const bf8*)&bpl[bi];
                }
                #pragma unroll
                for (int mt = 0; mt < 2; ++mt) {
                    int ad = ra[mt] + kk * 32 + qo8;
                    Ah[mt] = *(const bf8*)&XTh[ad];
                    Al[mt] = *(const bf8*)&XTl[ad];
                }
                #pragma unroll
                for (int mt = 0; mt < 2; ++mt)
                    #pragma unroll
                    for (int nt = 0; nt < 2; ++nt) {
                        accp[mt][nt] = MFMA(Ah[mt], Bh[nt], accp[mt][nt]);
                        accp[mt][nt] = MFMA(Ah[mt], Bl[nt], accp[mt][nt]);
                        accp[mt][nt] = MFMA(Al[mt], Bh[nt], accp[mt][nt]);
                    }
            }
        }
        // D[p][oc] -> s_out (reuse s_qk region): [oc*68 + p]
        #pragma unroll
        for (int nt = 0; nt < 2; ++nt) {
            int oc = (nh * 2 + nt) * 16 + col;
            #pragma unroll
            for (int mt = 0; mt < 2; ++mt) {
                int p0 = (mh * 2 + mt) * 16 + quad * 4;
                #pragma unroll
                for (int r = 0; r < 4; ++r) s_qk[oc * 68 + p0 + r] = accp[mt][nt][r];
            }
        }
    }
    __syncthreads();

    // ---- P8: window reverse + roll, coalesced image-order stores ----
    #pragma unroll
    for (int k = 0; k < 16; ++k) {
        int o = tid + k * 256;
        int hi = o >> 11, r = (o >> 8) & 7, lo = (o >> 3) & 31, s = o & 7;
        int c2 = hi * 32 + lo;
        float v = s_qk[c2 * 68 + r * 8 + s];
        int h2 = t * 16 + hi * 8 + r, w2 = lo * 8 + s;
        out[base + (size_t)((h2 + roll) & 255) * 256 + ((w2 + roll) & 255)] = v;
    }
}

extern "C" void kernel_launch(void* const* d_in, const int* in_sizes, int n_in,
                              void* d_out, int out_size, void* d_ws, size_t ws_size,
                              hipStream_t stream)
{
    const float* x      = (const float*)d_in[0];
    const float* wqkv0  = (const float*)d_in[1];
    const float* wdw0   = (const float*)d_in[2];
    const float* wproj0 = (const float*)d_in[3];
    const float* wqkv1  = (const float*)d_in[4];
    const float* wdw1   = (const float*)d_in[5];
    const float* wproj1 = (const float*)d_in[6];
    float* out = (float*)d_out;

    float* tmp = (float*)d_ws;                       // 33,554,432 floats (134 MB)
    short* fb  = (short*)(tmp + 33554432);           // weight fragments (bf16 bits)
    short* bq0h = fb;                                // 12288 each
    short* bq0l = fb + 12288;
    short* bq1h = fb + 24576;
    short* bq1l = fb + 36864;
    short* bp0h = fb + 49152;                        // 36864 each
    short* bp0l = fb + 86016;
    short* bp1h = fb + 122880;
    short* bp1l = fb + 159744;

    hipLaunchKernelGGL(k_fq, dim3(24), dim3(512), 0, stream, wqkv0, bq0h, bq0l);
    hipLaunchKernelGGL(k_fq, dim3(24), dim3(512), 0, stream, wqkv1, bq1h, bq1l);
    hipLaunchKernelGGL(k_fp, dim3(72), dim3(512), 0, stream, wproj0, bp0h, bp0l);
    hipLaunchKernelGGL(k_fp, dim3(72), dim3(512), 0, stream, wproj1, bp1h, bp1l);

    // pass 1: x -> tmp (no shift/mask/roll)
    hipLaunchKernelGGL(k_fused, dim3(8192), dim3(256), 0, stream,
                       x, bq0h, bq0l, wdw0, bp0h, bp0l, tmp, 0, 0, 0);
    // pass 2: tmp -> out (shift +4 read, Swin mask, roll +4 write)
    hipLaunchKernelGGL(k_fused, dim3(8192), dim3(256), 0, stream,
                       tmp, bq1h, bq1l, wdw1, bp1h, bp1l, out, 4, 1, 4);
}

// Round 4
// 855.364 us; speedup vs baseline: 5.0629x; 1.3688x over previous
//
#include <hip/hip_runtime.h>

// LocalAttention (Swin scrambled-window variant) — all four GEMMs on MFMA.
// Window map (verified pass R2/R3): n=b*1024+c*16+t ; c2=hi*32+lo ; p=r*8+s ;
// h=16t+8hi+r ; w=8lo+s ; mask index = n&1023.
// l2norm folds into k:  attn[i][j] = sum_c q[c][i] * (k[c][j]*0.125/(nq_c*nk_c)).
// Split-bf16 everywhere: x=hi+lo, D += Ah*Bh + Ah*Bl + Al*Bh (rel err ~2^-18).
//
// Phases (one block = one window, 9 barriers):
//  P1 load+split -> XTin[p][c]      TR  transpose q,k -> qT/kT [pixel][c] bf16
//  P2 MFMA 1x1 qkv -> fp32 planes   VB  v regs -> vbf [c][p] bf16
//  DWc dw3x3 -> regs (+norms)       P5  MFMA QK^T + mask + softmax -> PT[j][i]
//  DWw q,k(scaled) -> planes        P6  MFMA V*A -> XT[p][c]
//                                   P7  MFMA proj (9 shifted GEMMs) -> projo
//                                   P8  window-reverse(+roll) store

typedef __attribute__((ext_vector_type(8))) short bf8;
typedef __attribute__((ext_vector_type(4))) float f32x4;
#define MFMA(a, b, c) __builtin_amdgcn_mfma_f32_16x16x32_bf16(a, b, c, 0, 0, 0)

__device__ __forceinline__ void bsplit(float f, short& h, short& l) {
    unsigned u = __float_as_uint(f);
    unsigned hb = (u + 0x7FFFu + ((u >> 16) & 1u)) >> 16;
    float hf = __uint_as_float(hb << 16);
    float r = f - hf;
    unsigned u2 = __float_as_uint(r);
    unsigned lb = (u2 + 0x7FFFu + ((u2 >> 16) & 1u)) >> 16;
    h = (short)hb; l = (short)lb;
}
__device__ __forceinline__ void bsplit2(float a, float b, unsigned& hw, unsigned& lw) {
    short ha, la, hb_, lb_;
    bsplit(a, ha, la); bsplit(b, hb_, lb_);
    hw = (unsigned)(unsigned short)ha | ((unsigned)(unsigned short)hb_ << 16);
    lw = (unsigned)(unsigned short)la | ((unsigned)(unsigned short)lb_ << 16);
}

// ---- qkv 1x1 weight fragments: [kk(2)][tt(12)][lane(64)][j(8)]  B[n=oc][k=ic] ----
__global__ void k_fq(const float* __restrict__ wq, short* __restrict__ oh, short* __restrict__ ol) {
    int bx = blockIdx.x;                 // kk*12 + tt
    int kk = bx / 12, tt = bx % 12;
    int tid = threadIdx.x;               // 512
    int lane = tid >> 3, j = tid & 7;
    int oc = tt * 16 + (lane & 15);
    int ic = kk * 32 + ((lane >> 4) << 3) + j;
    short h, l; bsplit(wq[oc * 64 + ic], h, l);
    oh[bx * 512 + tid] = h; ol[bx * 512 + tid] = l;
}
// ---- proj 3x3 weight fragments: [tap(9)][kk(2)][tt(4)][lane(64)][j(8)] ----
__global__ void k_fp(const float* __restrict__ wp, short* __restrict__ oh, short* __restrict__ ol) {
    int bx = blockIdx.x;                 // tap*8 + kk*4 + tt
    int tap = bx >> 3, kk = (bx >> 2) & 1, tt = bx & 3;
    int tid = threadIdx.x;
    int lane = tid >> 3, j = tid & 7;
    int oc = tt * 16 + (lane & 15);
    int ic = kk * 32 + ((lane >> 4) << 3) + j;
    short h, l; bsplit(wp[(oc * 64 + ic) * 9 + tap], h, l);
    oh[bx * 512 + tid] = h; ol[bx * 512 + tid] = l;
}

// dw3x3 for a channel pair, one output row (8 px), window-local zero pad.
__device__ __forceinline__ void dw_pair(const float* planes, const float* wdw,
                                        int ch0, int row, float o[2][8]) {
    #pragma unroll
    for (int chi = 0; chi < 2; ++chi) {
        const float* pl = planes + (ch0 + chi) * 72;
        const float* wd = wdw + (ch0 + chi) * 9;
        float w9[9];
        #pragma unroll
        for (int tp = 0; tp < 9; ++tp) w9[tp] = wd[tp];
        float e[3][10];
        #pragma unroll
        for (int k3 = 0; k3 < 3; ++k3) {
            int rr = row - 1 + k3;
            e[k3][0] = 0.f; e[k3][9] = 0.f;
            if ((unsigned)rr < 8u) {
                float4 a = *(const float4*)&pl[rr * 8];
                float4 b = *(const float4*)&pl[rr * 8 + 4];
                e[k3][1] = a.x; e[k3][2] = a.y; e[k3][3] = a.z; e[k3][4] = a.w;
                e[k3][5] = b.x; e[k3][6] = b.y; e[k3][7] = b.z; e[k3][8] = b.w;
            } else {
                #pragma unroll
                for (int q2 = 1; q2 < 9; ++q2) e[k3][q2] = 0.f;
            }
        }
        #pragma unroll
        for (int s = 0; s < 8; ++s) {
            float a = 0.f;
            #pragma unroll
            for (int k3 = 0; k3 < 3; ++k3)
                #pragma unroll
                for (int dx = 0; dx < 3; ++dx)
                    a = fmaf(w9[k3 * 3 + dx], e[k3][s + dx], a);
            o[chi][s] = a;
        }
    }
}

__global__ __launch_bounds__(256, 2)
void k_fused(const float* __restrict__ in,
             const short* __restrict__ bqh, const short* __restrict__ bql,
             const float* __restrict__ wdw,
             const short* __restrict__ bph, const short* __restrict__ bpl,
             float* __restrict__ out, int shift, int use_mask, int roll)
{
    // Region plan (74016 B total, overlaid by live-range):
    //  [0,55296)   planes: 192x72 fp32 (P2 out, dw in/out, TR in)
    //    post-TR:  vbh/vbl [0,18432) ; PTh/PTl [18432,36864) ; kTh/kTl [36864,55296)
    //    post-P6:  projo (64x72 fp32) at [0,18432)
    //  [55296,74016) XT: 65x72 bf16 hi/lo — XTin -> qT -> attn-out(+zero row 64)
    __shared__ __align__(16) char smem[74016];
    float* planes = (float*)smem;
    short* vbh = (short*)smem;
    short* vbl = (short*)(smem + 9216);
    short* PTh = (short*)(smem + 18432);
    short* PTl = (short*)(smem + 27648);
    short* kTh = (short*)(smem + 36864);
    short* kTl = (short*)(smem + 46080);
    short* XTh = (short*)(smem + 55296);
    short* XTl = (short*)(smem + 55296 + 9360);
    float* projo = (float*)smem;

    const int tid = threadIdx.x, lane = tid & 63, wv = tid >> 6;
    const int col = lane & 15, quad = lane >> 4, qo8 = quad * 8;
    const int mh = wv & 1, nh = wv >> 1;
    const int n = blockIdx.x;
    const int b = n >> 10, c = (n >> 4) & 63, t = n & 15;
    const size_t base = ((size_t)(b * 64 + c)) << 16;

    // ---- P1: load window (shift folded), split, XTin[p][c2] ----
    #pragma unroll
    for (int k = 0; k < 16; ++k) {
        int o = tid + k * 256;
        int hi = o >> 11, r = (o >> 8) & 7, lo = (o >> 3) & 31, s = o & 7;
        int h2 = t * 16 + hi * 8 + r, w2 = lo * 8 + s;
        float v = in[base + (size_t)((h2 + shift) & 255) * 256 + ((w2 + shift) & 255)];
        short hh, ll; bsplit(v, hh, ll);
        int p = r * 8 + s, c2 = hi * 32 + lo;
        XTh[p * 72 + c2] = hh; XTl[p * 72 + c2] = ll;
    }
    __syncthreads();   // (1)

    // ---- P2: MFMA 1x1. M=p, N=oc(192), K=ic(64). wave: 2 m-tiles x 6 n-tiles ----
    {
        f32x4 acc[2][6];
        #pragma unroll
        for (int mt = 0; mt < 2; ++mt)
            #pragma unroll
            for (int nt = 0; nt < 6; ++nt) acc[mt][nt] = (f32x4){0.f, 0.f, 0.f, 0.f};
        #pragma unroll
        for (int kk = 0; kk < 2; ++kk) {
            bf8 Ah[2], Al[2];
            #pragma unroll
            for (int mt = 0; mt < 2; ++mt) {
                int ad = ((mh * 2 + mt) * 16 + col) * 72 + kk * 32 + qo8;
                Ah[mt] = *(const bf8*)&XTh[ad];
                Al[mt] = *(const bf8*)&XTl[ad];
            }
            #pragma unroll
            for (int nt = 0; nt < 6; ++nt) {
                int tt = nh * 6 + nt;
                bf8 Bh = *(const bf8*)&bqh[((kk * 12 + tt) * 64 + lane) * 8];
                bf8 Bl = *(const bf8*)&bql[((kk * 12 + tt) * 64 + lane) * 8];
                #pragma unroll
                for (int mt = 0; mt < 2; ++mt) {
                    acc[mt][nt] = MFMA(Ah[mt], Bh, acc[mt][nt]);
                    acc[mt][nt] = MFMA(Ah[mt], Bl, acc[mt][nt]);
                    acc[mt][nt] = MFMA(Al[mt], Bh, acc[mt][nt]);
                }
            }
        }
        #pragma unroll
        for (int nt = 0; nt < 6; ++nt) {
            int oc = (nh * 6 + nt) * 16 + col;
            #pragma unroll
            for (int mt = 0; mt < 2; ++mt) {
                int p0 = (mh * 2 + mt) * 16 + quad * 4;
                *(f32x4*)&planes[oc * 72 + p0] = acc[mt][nt];   // b128, conflict-free
            }
        }
    }
    __syncthreads();   // (2)

    // ---- DWc: dw3x3 into regs; per-channel norms via 8-lane shfl; fold scale into k ----
    const int cp = tid >> 3, rrow = tid & 7;
    float dq[2][8], dk[2][8], dv[2][8];
    float nq[2];
    dw_pair(planes, wdw, 2 * cp, rrow, dq);
    #pragma unroll
    for (int chi = 0; chi < 2; ++chi) {
        float ss = 0.f;
        #pragma unroll
        for (int s = 0; s < 8; ++s) ss = fmaf(dq[chi][s], dq[chi][s], ss);
        ss += __shfl_xor(ss, 1); ss += __shfl_xor(ss, 2); ss += __shfl_xor(ss, 4);
        nq[chi] = fmaxf(sqrtf(ss), 1e-12f);
    }
    dw_pair(planes, wdw, 64 + 2 * cp, rrow, dk);
    #pragma unroll
    for (int chi = 0; chi < 2; ++chi) {
        float ss = 0.f;
        #pragma unroll
        for (int s = 0; s < 8; ++s) ss = fmaf(dk[chi][s], dk[chi][s], ss);
        ss += __shfl_xor(ss, 1); ss += __shfl_xor(ss, 2); ss += __shfl_xor(ss, 4);
        float nk = fmaxf(sqrtf(ss), 1e-12f);
        float sc = 0.125f / (nq[chi] * nk);
        #pragma unroll
        for (int s = 0; s < 8; ++s) dk[chi][s] *= sc;
    }
    dw_pair(planes, wdw, 128 + 2 * cp, rrow, dv);
    __syncthreads();   // (3a) all stencil reads complete

    // ---- DWw: q, k(scaled) back to planes (b128 rows, conflict-free); v stays in regs ----
    #pragma unroll
    for (int chi = 0; chi < 2; ++chi) {
        float* dstq = planes + (2 * cp + chi) * 72 + rrow * 8;
        *(float4*)dstq       = (float4){dq[chi][0], dq[chi][1], dq[chi][2], dq[chi][3]};
        *(float4*)(dstq + 4) = (float4){dq[chi][4], dq[chi][5], dq[chi][6], dq[chi][7]};
        float* dstk = planes + (64 + 2 * cp + chi) * 72 + rrow * 8;
        *(float4*)dstk       = (float4){dk[chi][0], dk[chi][1], dk[chi][2], dk[chi][3]};
        *(float4*)(dstk + 4) = (float4){dk[chi][4], dk[chi][5], dk[chi][6], dk[chi][7]};
    }
    __syncthreads();   // (3b)

    // ---- TR: transpose q,k planes -> qT(=XT region) / kT  [pixel][c] bf16 split ----
    #pragma unroll
    for (int it2 = 0; it2 < 8; ++it2) {
        int pq = wv * 4 + ((it2 + (lane >> 2)) & 3);   // rotation spreads bank windows
        const float* src = planes + (lane + ((it2 >= 4) ? 64 : 0)) * 72 + pq * 4;
        float4 vle = *(const float4*)src;
        short* dh = (it2 < 4) ? XTh : kTh;
        short* dl = (it2 < 4) ? XTl : kTl;
        float vv[4] = {vle.x, vle.y, vle.z, vle.w};
        #pragma unroll
        for (int j = 0; j < 4; ++j) {
            short hh, ll; bsplit(vv[j], hh, ll);
            dh[(pq * 4 + j) * 72 + lane] = hh;
            dl[(pq * 4 + j) * 72 + lane] = ll;
        }
    }
    // zero row 64 of XT region (pad row for P7's shifted reads)
    if (tid < 36) { ((unsigned*)&XTh[64 * 72])[tid] = 0u; ((unsigned*)&XTl[64 * 72])[tid] = 0u; }
    __syncthreads();   // (4)

    // ---- VB: v regs -> vbf [c][p] bf16 split (b128 rows, conflict-free) ----
    #pragma unroll
    for (int chi = 0; chi < 2; ++chi) {
        unsigned hw[4], lw[4];
        #pragma unroll
        for (int q2 = 0; q2 < 4; ++q2) bsplit2(dv[chi][2 * q2], dv[chi][2 * q2 + 1], hw[q2], lw[q2]);
        int ad = (2 * cp + chi) * 72 + rrow * 8;
        *(uint4*)&vbh[ad] = (uint4){hw[0], hw[1], hw[2], hw[3]};
        *(uint4*)&vbl[ad] = (uint4){lw[0], lw[1], lw[2], lw[3]};
    }

    // ---- P5: MFMA QK^T (M=i rows wv*16.., N=j all 64, K=c) + mask + softmax ----
    f32x4 at[4];
    #pragma unroll
    for (int nt = 0; nt < 4; ++nt) at[nt] = (f32x4){0.f, 0.f, 0.f, 0.f};
    {
        bf8 Ah[2], Al[2];
        #pragma unroll
        for (int kk = 0; kk < 2; ++kk) {
            int ad = (wv * 16 + col) * 72 + kk * 32 + qo8;
            Ah[kk] = *(const bf8*)&XTh[ad];   // qT
            Al[kk] = *(const bf8*)&XTl[ad];
        }
        #pragma unroll
        for (int kk = 0; kk < 2; ++kk)
            #pragma unroll
            for (int nt = 0; nt < 4; ++nt) {
                int ad = (nt * 16 + col) * 72 + kk * 32 + qo8;
                bf8 Bh = *(const bf8*)&kTh[ad];
                bf8 Bl = *(const bf8*)&kTl[ad];
                at[nt] = MFMA(Ah[kk], Bh, at[nt]);
                at[nt] = MFMA(Ah[kk], Bl, at[nt]);
                at[nt] = MFMA(Al[kk], Bh, at[nt]);
            }
    }
    if (use_mask) {
        const int widx = n & 1023;
        const int hn_m = widx >> 5, wn_m = widx & 31;
        #pragma unroll
        for (int nt = 0; nt < 4; ++nt) {
            int j = nt * 16 + col;
            int rj = ((hn_m == 31) ? (((j >> 3) < 4) ? 1 : 2) : 0) * 3
                   + ((wn_m == 31) ? (((j & 7) < 4) ? 1 : 2) : 0);
            #pragma unroll
            for (int rg = 0; rg < 4; ++rg) {
                int i = wv * 16 + quad * 4 + rg;
                int ri = ((hn_m == 31) ? (((i >> 3) < 4) ? 1 : 2) : 0) * 3
                       + ((wn_m == 31) ? (((i & 7) < 4) ? 1 : 2) : 0);
                if (ri != rj) at[nt][rg] = at[nt][rg] - 100.f;
            }
        }
    }
    float Pv[4][4];
    #pragma unroll
    for (int rg = 0; rg < 4; ++rg) {
        float m = fmaxf(fmaxf(at[0][rg], at[1][rg]), fmaxf(at[2][rg], at[3][rg]));
        m = fmaxf(m, __shfl_xor(m, 1)); m = fmaxf(m, __shfl_xor(m, 2));
        m = fmaxf(m, __shfl_xor(m, 4)); m = fmaxf(m, __shfl_xor(m, 8));
        float e0 = __expf(at[0][rg] - m), e1 = __expf(at[1][rg] - m);
        float e2 = __expf(at[2][rg] - m), e3 = __expf(at[3][rg] - m);
        float s = e0 + e1 + e2 + e3;
        s += __shfl_xor(s, 1); s += __shfl_xor(s, 2);
        s += __shfl_xor(s, 4); s += __shfl_xor(s, 8);
        float is = 1.0f / s;
        Pv[0][rg] = e0 * is; Pv[1][rg] = e1 * is; Pv[2][rg] = e2 * is; Pv[3][rg] = e3 * is;
    }
    __syncthreads();   // (5) all qT/kT reads done

    // ---- PT write: PT[j][i] bf16 split (2-way, free) ----
    #pragma unroll
    for (int nt = 0; nt < 4; ++nt) {
        int j = nt * 16 + col;
        #pragma unroll
        for (int rp = 0; rp < 2; ++rp) {
            unsigned hw, lw; bsplit2(Pv[nt][2 * rp], Pv[nt][2 * rp + 1], hw, lw);
            int ad = j * 72 + wv * 16 + quad * 4 + 2 * rp;
            *(unsigned*)&PTh[ad] = hw; *(unsigned*)&PTl[ad] = lw;
        }
    }
    __syncthreads();   // (6)

    // ---- P6: MFMA V*A. M=c, N=j, K=i. A=vbf[c][i], B=PT[j][i]. D -> XT[p=j][c] ----
    {
        f32x4 av[2][2];
        #pragma unroll
        for (int mt = 0; mt < 2; ++mt)
            #pragma unroll
            for (int nt = 0; nt < 2; ++nt) av[mt][nt] = (f32x4){0.f, 0.f, 0.f, 0.f};
        #pragma unroll
        for (int kk = 0; kk < 2; ++kk) {
            bf8 Ah[2], Al[2], Bh[2], Bl[2];
            #pragma unroll
            for (int mt = 0; mt < 2; ++mt) {
                int ad = ((mh * 2 + mt) * 16 + col) * 72 + kk * 32 + qo8;
                Ah[mt] = *(const bf8*)&vbh[ad];
                Al[mt] = *(const bf8*)&vbl[ad];
            }
            #pragma unroll
            for (int nt = 0; nt < 2; ++nt) {
                int ad = ((nh * 2 + nt) * 16 + col) * 72 + kk * 32 + qo8;
                Bh[nt] = *(const bf8*)&PTh[ad];
                Bl[nt] = *(const bf8*)&PTl[ad];
            }
            #pragma unroll
            for (int mt = 0; mt < 2; ++mt)
                #pragma unroll
                for (int nt = 0; nt < 2; ++nt) {
                    av[mt][nt] = MFMA(Ah[mt], Bh[nt], av[mt][nt]);
                    av[mt][nt] = MFMA(Ah[mt], Bl[nt], av[mt][nt]);
                    av[mt][nt] = MFMA(Al[mt], Bh[nt], av[mt][nt]);
                }
        }
        #pragma unroll
        for (int nt = 0; nt < 2; ++nt) {
            int j = (nh * 2 + nt) * 16 + col;
            #pragma unroll
            for (int mt = 0; mt < 2; ++mt) {
                int c0 = (mh * 2 + mt) * 16 + quad * 4;
                #pragma unroll
                for (int rp = 0; rp < 2; ++rp) {
                    unsigned hw, lw; bsplit2(av[mt][nt][2 * rp], av[mt][nt][2 * rp + 1], hw, lw);
                    *(unsigned*)&XTh[j * 72 + c0 + 2 * rp] = hw;
                    *(unsigned*)&XTl[j * 72 + c0 + 2 * rp] = lw;
                }
            }
        }
    }
    __syncthreads();   // (7)

    // ---- P7: MFMA proj conv = 9 shifted GEMMs. M=p, N=oc, K=ic ----
    {
        f32x4 ap[2][2];
        #pragma unroll
        for (int mt = 0; mt < 2; ++mt)
            #pragma unroll
            for (int nt = 0; nt < 2; ++nt) ap[mt][nt] = (f32x4){0.f, 0.f, 0.f, 0.f};
        const int smc = col & 7;
        #pragma unroll 1
        for (int tap = 0; tap < 9; ++tap) {
            int dy = (tap >= 6) ? 1 : ((tap >= 3) ? 0 : -1);
            int dx = tap - (dy + 1) * 3 - 1;
            int ra[2];
            #pragma unroll
            for (int mt = 0; mt < 2; ++mt) {
                int rr = (mh * 2 + mt) * 2 + (col >> 3) + dy;
                int ss = smc + dx;
                bool ok = ((unsigned)rr < 8u) && ((unsigned)ss < 8u);
                ra[mt] = (ok ? (rr * 8 + ss) : 64) * 72;   // row 64 = zeros
            }
            #pragma unroll
            for (int kk = 0; kk < 2; ++kk) {
                bf8 Bh[2], Bl[2], Ah[2], Al[2];
                #pragma unroll
                for (int nt = 0; nt < 2; ++nt) {
                    int bi = (((tap * 2 + kk) * 4 + (nh * 2 + nt)) * 64 + lane) * 8;
                    Bh[nt] = *(const bf8*)&bph[bi];
                    Bl[nt] = *(const bf8*)&bpl[bi];
                }
                #pragma unroll
                for (int mt = 0; mt < 2; ++mt) {
                    int ad = ra[mt] + kk * 32 + qo8;
                    Ah[mt] = *(const bf8*)&XTh[ad];
                    Al[mt] = *(const bf8*)&XTl[ad];
                }
                #pragma unroll
                for (int mt = 0; mt < 2; ++mt)
                    #pragma unroll
                    for (int nt = 0; nt < 2; ++nt) {
                        ap[mt][nt] = MFMA(Ah[mt], Bh[nt], ap[mt][nt]);
                        ap[mt][nt] = MFMA(Ah[mt], Bl[nt], ap[mt][nt]);
                        ap[mt][nt] = MFMA(Al[mt], Bh[nt], ap[mt][nt]);
                    }
            }
        }
        #pragma unroll
        for (int nt = 0; nt < 2; ++nt) {
            int oc = (nh * 2 + nt) * 16 + col;
            #pragma unroll
            for (int mt = 0; mt < 2; ++mt) {
                int p0 = (mh * 2 + mt) * 16 + quad * 4;
                *(f32x4*)&projo[oc * 72 + p0] = ap[mt][nt];
            }
        }
    }
    __syncthreads();   // (8)

    // ---- P8: window reverse + roll, coalesced image-order stores ----
    #pragma unroll
    for (int k = 0; k < 16; ++k) {
        int o = tid + k * 256;
        int hi = o >> 11, r = (o >> 8) & 7, lo = (o >> 3) & 31, s = o & 7;
        int c2 = hi * 32 + lo;
        float v = projo[c2 * 72 + r * 8 + s];
        int h2 = t * 16 + hi * 8 + r, w2 = lo * 8 + s;
        out[base + (size_t)((h2 + roll) & 255) * 256 + ((w2 + roll) & 255)] = v;
    }
}

extern "C" void kernel_launch(void* const* d_in, const int* in_sizes, int n_in,
                              void* d_out, int out_size, void* d_ws, size_t ws_size,
                              hipStream_t stream)
{
    const float* x      = (const float*)d_in[0];
    const float* wqkv0  = (const float*)d_in[1];
    const float* wdw0   = (const float*)d_in[2];
    const float* wproj0 = (const float*)d_in[3];
    const float* wqkv1  = (const float*)d_in[4];
    const float* wdw1   = (const float*)d_in[5];
    const float* wproj1 = (const float*)d_in[6];
    float* out = (float*)d_out;

    float* tmp = (float*)d_ws;                       // 33,554,432 floats (134 MB)
    short* fb  = (short*)(tmp + 33554432);
    short* bq0h = fb;                                // 12288 each
    short* bq0l = fb + 12288;
    short* bq1h = fb + 24576;
    short* bq1l = fb + 36864;
    short* bp0h = fb + 49152;                        // 36864 each
    short* bp0l = fb + 86016;
    short* bp1h = fb + 122880;
    short* bp1l = fb + 159744;

    hipLaunchKernelGGL(k_fq, dim3(24), dim3(512), 0, stream, wqkv0, bq0h, bq0l);
    hipLaunchKernelGGL(k_fq, dim3(24), dim3(512), 0, stream, wqkv1, bq1h, bq1l);
    hipLaunchKernelGGL(k_fp, dim3(72), dim3(512), 0, stream, wproj0, bp0h, bp0l);
    hipLaunchKernelGGL(k_fp, dim3(72), dim3(512), 0, stream, wproj1, bp1h, bp1l);

    // pass 1: x -> tmp (no shift/mask/roll)
    hipLaunchKernelGGL(k_fused, dim3(8192), dim3(256), 0, stream,
                       x, bq0h, bq0l, wdw0, bp0h, bp0l, tmp, 0, 0, 0);
    // pass 2: tmp -> out (shift +4 read, Swin mask, roll +4 write)
    hipLaunchKernelGGL(k_fused, dim3(8192), dim3(256), 0, stream,
                       tmp, bq1h, bq1l, wdw1, bp1h, bp1l, out, 4, 1, 4);
}